// Round 1
// baseline (462.547 us; speedup 1.0000x reference)
//
#include <hip/hip_runtime.h>
#include <hip/hip_bf16.h>
#include <math.h>

#define H 1024
#define FF 2048
#define E 8
#define T 2048
#define NSLOT (2*T)
#define SLOT_PAD 128

typedef __attribute__((ext_vector_type(8))) short s16x8;
typedef __attribute__((ext_vector_type(4))) float f32x4;

static __device__ __forceinline__ unsigned short f2bf(float f) {
    union { float f; unsigned u; } v; v.f = f;
    unsigned r = v.u + 0x7fff + ((v.u >> 16) & 1);
    return (unsigned short)(r >> 16);
}

// ---------------- Router: fp32 logits, top-2, renormalized weights ----------------
__global__ __launch_bounds__(256) void router_kernel(
    const float* __restrict__ x, const float* __restrict__ gw,
    float* __restrict__ logits_out, int* __restrict__ top_id,
    float* __restrict__ top_w, int* __restrict__ counts)
{
    int t = blockIdx.x;
    int tid = threadIdx.x;
    int e = tid >> 5;          // 8 groups of 32 lanes, one expert each
    int l32 = tid & 31;
    const float* xr = x + (size_t)t * H;
    const float* gr = gw + (size_t)e * H;
    float s = 0.f;
    for (int h = l32; h < H; h += 32) s += xr[h] * gr[h];
    for (int off = 16; off; off >>= 1) s += __shfl_down(s, off, 32);
    __shared__ float lg[E];
    if (l32 == 0) lg[e] = s;
    __syncthreads();
    if (tid < E) logits_out[(size_t)t * E + tid] = lg[tid];
    if (tid == 0) {
        int i1 = 0; float b1 = lg[0];
        for (int i = 1; i < E; ++i) if (lg[i] > b1) { b1 = lg[i]; i1 = i; }
        int i2 = -1; float b2 = -INFINITY;
        for (int i = 0; i < E; ++i) if (i != i1 && lg[i] > b2) { b2 = lg[i]; i2 = i; }
        // softmax over full set then renormalize over top-2 == softmax over top-2
        float p2 = expf(b2 - b1);
        float inv = 1.f / (1.f + p2);
        top_id[2*t]   = i1;  top_id[2*t+1] = i2;
        top_w[2*t]    = inv; top_w[2*t+1]  = p2 * inv;
        atomicAdd(&counts[i1], 1);
        atomicAdd(&counts[i2], 1);
    }
}

// ---------------- Exclusive scan over 8 counts ----------------
__global__ void scan_kernel(const int* __restrict__ counts,
                            int* __restrict__ offsets, int* __restrict__ cursors)
{
    if (threadIdx.x == 0) {
        int acc = 0;
        for (int i = 0; i < E; ++i) { offsets[i] = acc; acc += counts[i]; }
        offsets[E] = acc;
    }
    if (threadIdx.x < E) cursors[threadIdx.x] = 0;
}

// ---------------- Assign slots + gather x rows as bf16 ----------------
__global__ __launch_bounds__(256) void assign_kernel(
    const float* __restrict__ x, const int* __restrict__ top_id,
    const float* __restrict__ top_w, const int* __restrict__ offsets,
    int* __restrict__ cursors, int* __restrict__ slot_token,
    float* __restrict__ slot_w, unsigned short* __restrict__ xg)
{
    int t = blockIdx.x, tid = threadIdx.x;
    __shared__ int pos[2];
    if (tid == 0) {
        for (int k = 0; k < 2; ++k) {
            int e = top_id[2*t + k];
            int p = offsets[e] + atomicAdd(&cursors[e], 1);
            slot_token[p] = t;
            slot_w[p] = top_w[2*t + k];
            pos[k] = p;
        }
    }
    __syncthreads();
    float4 xv = ((const float4*)(x + (size_t)t * H))[tid];
    ushort4 b;
    b.x = f2bf(xv.x); b.y = f2bf(xv.y); b.z = f2bf(xv.z); b.w = f2bf(xv.w);
    ((ushort4*)(xg + (size_t)pos[0] * H))[tid] = b;
    ((ushort4*)(xg + (size_t)pos[1] * H))[tid] = b;
}

// ---------------- GEMM1: mid = silu(xg @ w1^T) * (xg @ w3^T), per expert ----------------
// tile: 128 tokens x 64 f, BK=64 over H. 4 waves (2x2), wave = 64x32, dual acc.
__global__ __launch_bounds__(256) void gemm1_kernel(
    const unsigned short* __restrict__ xg,
    const float* __restrict__ w1, const float* __restrict__ w3,
    const int* __restrict__ offsets, unsigned short* __restrict__ mid)
{
    int e = blockIdx.z;
    int off = offsets[e];
    int cnt = offsets[e + 1] - off;
    int m0 = blockIdx.y * 128;
    if (m0 >= cnt) return;
    int f0 = blockIdx.x * 64;

    __shared__ __align__(16) unsigned short sx[128][72];
    __shared__ __align__(16) unsigned short s1[64][72];
    __shared__ __align__(16) unsigned short s3[64][72];

    int tid = threadIdx.x;
    int wave = tid >> 6, lane = tid & 63;
    int quad = lane >> 4, l16 = lane & 15;
    int wm = wave & 1, wn = wave >> 1;

    f32x4 acc1[4][2] = {{{0.f,0.f,0.f,0.f}}};
    f32x4 acc3[4][2] = {{{0.f,0.f,0.f,0.f}}};

    int sxr = tid >> 3, sxc = (tid & 7) * 8;   // 32 rows/pass, 8 bf16 per thread
    int swr = tid >> 2, swc = (tid & 3) * 16;  // 64 rows, 16 floats per thread

    const unsigned short* xgp = xg + (size_t)(off + m0 + sxr) * H + sxc;
    const float* w1p = w1 + ((size_t)e * FF + f0 + swr) * H + swc;
    const float* w3p = w3 + ((size_t)e * FF + f0 + swr) * H + swc;

    for (int k0 = 0; k0 < H; k0 += 64) {
        // stage x tile (already bf16)
        #pragma unroll
        for (int rr = 0; rr < 128; rr += 32) {
            uint4 v = *(const uint4*)(xgp + (size_t)rr * H + k0);
            *(uint4*)&sx[sxr + rr][sxc] = v;
        }
        // stage w1/w3 tiles (fp32 -> bf16)
        #pragma unroll
        for (int c = 0; c < 16; c += 4) {
            float4 a1 = *(const float4*)(w1p + k0 + c);
            float4 a3 = *(const float4*)(w3p + k0 + c);
            ushort4 c1, c3;
            c1.x = f2bf(a1.x); c1.y = f2bf(a1.y); c1.z = f2bf(a1.z); c1.w = f2bf(a1.w);
            c3.x = f2bf(a3.x); c3.y = f2bf(a3.y); c3.z = f2bf(a3.z); c3.w = f2bf(a3.w);
            *(ushort4*)&s1[swr][swc + c] = c1;
            *(ushort4*)&s3[swr][swc + c] = c3;
        }
        __syncthreads();
        #pragma unroll
        for (int ks = 0; ks < 2; ++ks) {
            int kk = ks * 32 + quad * 8;
            s16x8 a[4], b1[2], b3[2];
            #pragma unroll
            for (int i = 0; i < 4; ++i)
                a[i] = *(const s16x8*)&sx[wm * 64 + i * 16 + l16][kk];
            #pragma unroll
            for (int j = 0; j < 2; ++j) {
                b1[j] = *(const s16x8*)&s1[wn * 32 + j * 16 + l16][kk];
                b3[j] = *(const s16x8*)&s3[wn * 32 + j * 16 + l16][kk];
            }
            #pragma unroll
            for (int i = 0; i < 4; ++i)
                #pragma unroll
                for (int j = 0; j < 2; ++j) {
                    acc1[i][j] = __builtin_amdgcn_mfma_f32_16x16x32_bf16(a[i], b1[j], acc1[i][j], 0, 0, 0);
                    acc3[i][j] = __builtin_amdgcn_mfma_f32_16x16x32_bf16(a[i], b3[j], acc3[i][j], 0, 0, 0);
                }
        }
        __syncthreads();
    }

    // epilogue: mid = silu(h)*g, bf16
    #pragma unroll
    for (int i = 0; i < 4; ++i) {
        #pragma unroll
        for (int r = 0; r < 4; ++r) {
            int row = wm * 64 + i * 16 + quad * 4 + r;
            if (m0 + row < cnt) {
                size_t base = (size_t)(off + m0 + row) * FF + f0 + wn * 32;
                #pragma unroll
                for (int j = 0; j < 2; ++j) {
                    float h = acc1[i][j][r];
                    float g = acc3[i][j][r];
                    float v = h / (1.f + __expf(-h)) * g;
                    mid[base + j * 16 + l16] = f2bf(v);
                }
            }
        }
    }
}

// ---------------- GEMM2: out[token] += w * (mid @ w2^T), per expert ----------------
// tile: 128 slots x 64 h-cols, BK=64 over F.
__global__ __launch_bounds__(256) void gemm2_kernel(
    const unsigned short* __restrict__ mid, const float* __restrict__ w2,
    const int* __restrict__ offsets, const int* __restrict__ slot_token,
    const float* __restrict__ slot_w, float* __restrict__ out)
{
    int e = blockIdx.z;
    int off = offsets[e];
    int cnt = offsets[e + 1] - off;
    int m0 = blockIdx.y * 128;
    if (m0 >= cnt) return;
    int n0 = blockIdx.x * 64;

    __shared__ __align__(16) unsigned short sa[128][72];
    __shared__ __align__(16) unsigned short sb[64][72];

    int tid = threadIdx.x;
    int wave = tid >> 6, lane = tid & 63;
    int quad = lane >> 4, l16 = lane & 15;
    int wm = wave & 1, wn = wave >> 1;

    f32x4 acc[4][2] = {{{0.f,0.f,0.f,0.f}}};

    int sxr = tid >> 3, sxc = (tid & 7) * 8;
    int swr = tid >> 2, swc = (tid & 3) * 16;

    const unsigned short* ap = mid + (size_t)(off + m0 + sxr) * FF + sxc;
    const float* bp = w2 + ((size_t)e * H + n0 + swr) * FF + swc;

    for (int k0 = 0; k0 < FF; k0 += 64) {
        #pragma unroll
        for (int rr = 0; rr < 128; rr += 32) {
            uint4 v = *(const uint4*)(ap + (size_t)rr * FF + k0);
            *(uint4*)&sa[sxr + rr][sxc] = v;
        }
        #pragma unroll
        for (int c = 0; c < 16; c += 4) {
            float4 a = *(const float4*)(bp + k0 + c);
            ushort4 cb;
            cb.x = f2bf(a.x); cb.y = f2bf(a.y); cb.z = f2bf(a.z); cb.w = f2bf(a.w);
            *(ushort4*)&sb[swr][swc + c] = cb;
        }
        __syncthreads();
        #pragma unroll
        for (int ks = 0; ks < 2; ++ks) {
            int kk = ks * 32 + quad * 8;
            s16x8 a[4], b[2];
            #pragma unroll
            for (int i = 0; i < 4; ++i)
                a[i] = *(const s16x8*)&sa[wm * 64 + i * 16 + l16][kk];
            #pragma unroll
            for (int j = 0; j < 2; ++j)
                b[j] = *(const s16x8*)&sb[wn * 32 + j * 16 + l16][kk];
            #pragma unroll
            for (int i = 0; i < 4; ++i)
                #pragma unroll
                for (int j = 0; j < 2; ++j)
                    acc[i][j] = __builtin_amdgcn_mfma_f32_16x16x32_bf16(a[i], b[j], acc[i][j], 0, 0, 0);
        }
        __syncthreads();
    }

    // epilogue: weighted scatter-add into out
    #pragma unroll
    for (int i = 0; i < 4; ++i) {
        #pragma unroll
        for (int r = 0; r < 4; ++r) {
            int row = wm * 64 + i * 16 + quad * 4 + r;
            if (m0 + row < cnt) {
                int slot = off + m0 + row;
                int tok = slot_token[slot];
                float wgt = slot_w[slot];
                float* orow = out + (size_t)tok * H + n0 + wn * 32;
                #pragma unroll
                for (int j = 0; j < 2; ++j)
                    atomicAdd(&orow[j * 16 + l16], acc[i][j][r] * wgt);
            }
        }
    }
}

extern "C" void kernel_launch(void* const* d_in, const int* in_sizes, int n_in,
                              void* d_out, int out_size, void* d_ws, size_t ws_size,
                              hipStream_t stream) {
    const float* x  = (const float*)d_in[0];
    const float* gw = (const float*)d_in[1];
    const float* w1 = (const float*)d_in[2];
    const float* w2 = (const float*)d_in[3];
    const float* w3 = (const float*)d_in[4];
    float* out    = (float*)d_out;              // T*H
    float* logits = out + (size_t)T * H;        // T*E

    // workspace layout
    int* counts       = (int*)d_ws;             // [8]
    int* cursors      = counts + 8;             // [8]
    int* offsets      = cursors + 8;            // [9]
    int* top_id       = counts + 64;            // [2T]
    float* top_w      = (float*)(top_id + 2*T); // [2T]
    int* slot_token   = (int*)(top_w + 2*T);    // [NSLOT]
    float* slot_w     = (float*)(slot_token + NSLOT); // [NSLOT]
    unsigned short* xg  = (unsigned short*)(slot_w + NSLOT);       // [NSLOT+PAD][H]
    unsigned short* mid = xg + (size_t)(NSLOT + SLOT_PAD) * H;     // [NSLOT+PAD][F]

    hipMemsetAsync(counts, 0, 64 * sizeof(int), stream);
    hipMemsetAsync(out, 0, (size_t)T * H * sizeof(float), stream);

    router_kernel<<<T, 256, 0, stream>>>(x, gw, logits, top_id, top_w, counts);
    scan_kernel<<<1, 64, 0, stream>>>(counts, offsets, cursors);
    assign_kernel<<<T, 256, 0, stream>>>(x, top_id, top_w, offsets, cursors,
                                         slot_token, slot_w, xg);
    gemm1_kernel<<<dim3(FF / 64, 16, E), 256, 0, stream>>>(xg, w1, w3, offsets, mid);
    gemm2_kernel<<<dim3(H / 64, 16, E), 256, 0, stream>>>(mid, w2, offsets,
                                                          slot_token, slot_w, out);
}

// Round 2
// 426.327 us; speedup vs baseline: 1.0850x; 1.0850x over previous
//
#include <hip/hip_runtime.h>
#include <hip/hip_bf16.h>
#include <math.h>

#define H 1024
#define FF 2048
#define E 8
#define T 2048
#define NSLOT (2*T)
#define SLOT_PAD 128

typedef __attribute__((ext_vector_type(8))) short s16x8;
typedef __attribute__((ext_vector_type(4))) float f32x4;

static __device__ __forceinline__ unsigned short f2bf(float f) {
    union { float f; unsigned u; } v; v.f = f;
    unsigned r = v.u + 0x7fff + ((v.u >> 16) & 1);
    return (unsigned short)(r >> 16);
}
static __device__ __forceinline__ float bf2f(unsigned short s) {
    union { unsigned u; float f; } v; v.u = ((unsigned)s) << 16;
    return v.f;
}

typedef __attribute__((address_space(3))) unsigned int lds_uint;
typedef const __attribute__((address_space(1))) unsigned int glob_uint;
static __device__ __forceinline__ void gl_lds16(const void* g, void* l) {
    __builtin_amdgcn_global_load_lds((glob_uint*)g, (lds_uint*)l, 16, 0, 0);
}

// ---------------- Weight convert: fp32 -> bf16 (one streaming pass) ----------------
__global__ __launch_bounds__(256) void convert_kernel(
    const float* __restrict__ w1, const float* __restrict__ w3,
    const float* __restrict__ w2, unsigned short* __restrict__ w1b,
    unsigned short* __restrict__ w3b, unsigned short* __restrict__ w2b)
{
    const float* s; unsigned short* d;
    if (blockIdx.y == 0)      { s = w1; d = w1b; }
    else if (blockIdx.y == 1) { s = w3; d = w3b; }
    else                      { s = w2; d = w2b; }
    size_t i = ((size_t)blockIdx.x * 256 + threadIdx.x) * 8;
    float4 a = *(const float4*)(s + i);
    float4 b = *(const float4*)(s + i + 4);
    uint4 st;
    st.x = f2bf(a.x) | ((unsigned)f2bf(a.y) << 16);
    st.y = f2bf(a.z) | ((unsigned)f2bf(a.w) << 16);
    st.z = f2bf(b.x) | ((unsigned)f2bf(b.y) << 16);
    st.w = f2bf(b.z) | ((unsigned)f2bf(b.w) << 16);
    *(uint4*)(d + i) = st;
}

// ---------------- Router: fp32 logits, top-2, renormalized weights ----------------
__global__ __launch_bounds__(256) void router_kernel(
    const float* __restrict__ x, const float* __restrict__ gw,
    float* __restrict__ logits_out, int* __restrict__ top_id,
    float* __restrict__ top_w, int* __restrict__ counts)
{
    int t = blockIdx.x;
    int tid = threadIdx.x;
    int e = tid >> 5;
    int l32 = tid & 31;
    const float* xr = x + (size_t)t * H;
    const float* gr = gw + (size_t)e * H;
    float s = 0.f;
    for (int h = l32; h < H; h += 32) s += xr[h] * gr[h];
    for (int off = 16; off; off >>= 1) s += __shfl_down(s, off, 32);
    __shared__ float lg[E];
    if (l32 == 0) lg[e] = s;
    __syncthreads();
    if (tid < E) logits_out[(size_t)t * E + tid] = lg[tid];
    if (tid == 0) {
        int i1 = 0; float b1 = lg[0];
        for (int i = 1; i < E; ++i) if (lg[i] > b1) { b1 = lg[i]; i1 = i; }
        int i2 = -1; float b2 = -INFINITY;
        for (int i = 0; i < E; ++i) if (i != i1 && lg[i] > b2) { b2 = lg[i]; i2 = i; }
        float p2 = expf(b2 - b1);
        float inv = 1.f / (1.f + p2);
        top_id[2*t]   = i1;  top_id[2*t+1] = i2;
        top_w[2*t]    = inv; top_w[2*t+1]  = p2 * inv;
        atomicAdd(&counts[i1], 1);
        atomicAdd(&counts[i2], 1);
    }
}

// ---------------- Exclusive scan over 8 counts ----------------
__global__ void scan_kernel(const int* __restrict__ counts,
                            int* __restrict__ offsets, int* __restrict__ cursors)
{
    if (threadIdx.x == 0) {
        int acc = 0;
        for (int i = 0; i < E; ++i) { offsets[i] = acc; acc += counts[i]; }
        offsets[E] = acc;
    }
    if (threadIdx.x < E) cursors[threadIdx.x] = 0;
}

// ---------------- Assign slots + gather x rows as bf16 ----------------
__global__ __launch_bounds__(256) void assign_kernel(
    const float* __restrict__ x, const int* __restrict__ top_id,
    const int* __restrict__ offsets, int* __restrict__ cursors,
    int* __restrict__ top_pos, unsigned short* __restrict__ xg)
{
    int t = blockIdx.x, tid = threadIdx.x;
    __shared__ int pos[2];
    if (tid == 0) {
        for (int k = 0; k < 2; ++k) {
            int e = top_id[2*t + k];
            int p = offsets[e] + atomicAdd(&cursors[e], 1);
            top_pos[2*t + k] = p;
            pos[k] = p;
        }
    }
    __syncthreads();
    float4 xv = ((const float4*)(x + (size_t)t * H))[tid];
    ushort4 b;
    b.x = f2bf(xv.x); b.y = f2bf(xv.y); b.z = f2bf(xv.z); b.w = f2bf(xv.w);
    ((ushort4*)(xg + (size_t)pos[0] * H))[tid] = b;
    ((ushort4*)(xg + (size_t)pos[1] * H))[tid] = b;
}

// ---------------- GEMM1: mid = silu(xg @ w1b^T) * (xg @ w3b^T) ----------------
// tile 128 slots x 64 f, BK=64, global_load_lds staging, XOR-swizzled LDS.
__global__ __launch_bounds__(256) void gemm1_kernel(
    const unsigned short* __restrict__ xg,
    const unsigned short* __restrict__ w1b, const unsigned short* __restrict__ w3b,
    const int* __restrict__ offsets, unsigned short* __restrict__ mid)
{
    int e = blockIdx.z;
    int off = offsets[e];
    int cnt = offsets[e + 1] - off;
    int m0 = blockIdx.y * 128;
    if (m0 >= cnt) return;
    int f0 = blockIdx.x * 64;

    __shared__ __align__(16) unsigned short sx[128 * 64];
    __shared__ __align__(16) unsigned short s1[64 * 64];
    __shared__ __align__(16) unsigned short s3[64 * 64];

    int tid = threadIdx.x;
    int wv = tid >> 6, ln = tid & 63;
    int quad = ln >> 4, l16 = ln & 15;
    int wm = wv & 1, wn = wv >> 1;
    int xor7 = l16 & 7;

    // staging descriptors (physical LDS slot = lane order; XOR swizzle in source)
    const unsigned short* xsrc[4]; unsigned short* xdst[4];
    #pragma unroll
    for (int j = 0; j < 4; ++j) {
        int row = wv * 32 + j * 8 + (ln >> 3);
        int cl = (ln & 7) ^ (row & 7);
        xsrc[j] = xg + (size_t)(off + m0 + row) * H + cl * 8;
        xdst[j] = &sx[(wv * 32 + j * 8) * 64];
    }
    const unsigned short *w1s[2], *w3s[2]; unsigned short *d1[2], *d3[2];
    #pragma unroll
    for (int j = 0; j < 2; ++j) {
        int row = wv * 16 + j * 8 + (ln >> 3);
        int cl = (ln & 7) ^ (row & 7);
        w1s[j] = w1b + ((size_t)e * FF + f0 + row) * H + cl * 8;
        w3s[j] = w3b + ((size_t)e * FF + f0 + row) * H + cl * 8;
        d1[j] = &s1[(wv * 16 + j * 8) * 64];
        d3[j] = &s3[(wv * 16 + j * 8) * 64];
    }

    f32x4 acc1[4][2], acc3[4][2];
    #pragma unroll
    for (int i = 0; i < 4; ++i)
        #pragma unroll
        for (int j = 0; j < 2; ++j) {
            acc1[i][j] = (f32x4){0.f, 0.f, 0.f, 0.f};
            acc3[i][j] = (f32x4){0.f, 0.f, 0.f, 0.f};
        }

    for (int k0 = 0; k0 < H; k0 += 64) {
        #pragma unroll
        for (int j = 0; j < 4; ++j) gl_lds16(xsrc[j] + k0, xdst[j]);
        #pragma unroll
        for (int j = 0; j < 2; ++j) { gl_lds16(w1s[j] + k0, d1[j]); gl_lds16(w3s[j] + k0, d3[j]); }
        __syncthreads();
        #pragma unroll
        for (int ks = 0; ks < 2; ++ks) {
            int cph = ((quad + 4 * ks) ^ xor7) << 3;
            s16x8 a[4], b1v[2], b3v[2];
            #pragma unroll
            for (int i = 0; i < 4; ++i)
                a[i] = *(const s16x8*)&sx[(wm * 64 + i * 16 + l16) * 64 + cph];
            #pragma unroll
            for (int j = 0; j < 2; ++j) {
                b1v[j] = *(const s16x8*)&s1[(wn * 32 + j * 16 + l16) * 64 + cph];
                b3v[j] = *(const s16x8*)&s3[(wn * 32 + j * 16 + l16) * 64 + cph];
            }
            #pragma unroll
            for (int i = 0; i < 4; ++i)
                #pragma unroll
                for (int j = 0; j < 2; ++j) {
                    acc1[i][j] = __builtin_amdgcn_mfma_f32_16x16x32_bf16(a[i], b1v[j], acc1[i][j], 0, 0, 0);
                    acc3[i][j] = __builtin_amdgcn_mfma_f32_16x16x32_bf16(a[i], b3v[j], acc3[i][j], 0, 0, 0);
                }
        }
        __syncthreads();
    }

    #pragma unroll
    for (int i = 0; i < 4; ++i) {
        #pragma unroll
        for (int r = 0; r < 4; ++r) {
            int row = wm * 64 + i * 16 + quad * 4 + r;
            if (m0 + row < cnt) {
                size_t base = (size_t)(off + m0 + row) * FF + f0 + wn * 32;
                #pragma unroll
                for (int j = 0; j < 2; ++j) {
                    float h = acc1[i][j][r];
                    float g = acc3[i][j][r];
                    float v = h / (1.f + __expf(-h)) * g;
                    mid[base + j * 16 + l16] = f2bf(v);
                }
            }
        }
    }
}

// ---------------- GEMM2: y[slot] = mid[slot] @ w2b^T (bf16 out, no atomics) ----------------
__global__ __launch_bounds__(256) void gemm2_kernel(
    const unsigned short* __restrict__ mid, const unsigned short* __restrict__ w2b,
    const int* __restrict__ offsets, unsigned short* __restrict__ y)
{
    int e = blockIdx.z;
    int off = offsets[e];
    int cnt = offsets[e + 1] - off;
    int m0 = blockIdx.y * 128;
    if (m0 >= cnt) return;
    int n0 = blockIdx.x * 64;

    __shared__ __align__(16) unsigned short sa[128 * 64];
    __shared__ __align__(16) unsigned short sb[64 * 64];

    int tid = threadIdx.x;
    int wv = tid >> 6, ln = tid & 63;
    int quad = ln >> 4, l16 = ln & 15;
    int wm = wv & 1, wn = wv >> 1;
    int xor7 = l16 & 7;

    const unsigned short* asrc[4]; unsigned short* adst[4];
    #pragma unroll
    for (int j = 0; j < 4; ++j) {
        int row = wv * 32 + j * 8 + (ln >> 3);
        int cl = (ln & 7) ^ (row & 7);
        asrc[j] = mid + (size_t)(off + m0 + row) * FF + cl * 8;
        adst[j] = &sa[(wv * 32 + j * 8) * 64];
    }
    const unsigned short* bsrc[2]; unsigned short* bdst[2];
    #pragma unroll
    for (int j = 0; j < 2; ++j) {
        int row = wv * 16 + j * 8 + (ln >> 3);
        int cl = (ln & 7) ^ (row & 7);
        bsrc[j] = w2b + ((size_t)e * H + n0 + row) * FF + cl * 8;
        bdst[j] = &sb[(wv * 16 + j * 8) * 64];
    }

    f32x4 acc[4][2];
    #pragma unroll
    for (int i = 0; i < 4; ++i)
        #pragma unroll
        for (int j = 0; j < 2; ++j) acc[i][j] = (f32x4){0.f, 0.f, 0.f, 0.f};

    for (int k0 = 0; k0 < FF; k0 += 64) {
        #pragma unroll
        for (int j = 0; j < 4; ++j) gl_lds16(asrc[j] + k0, adst[j]);
        #pragma unroll
        for (int j = 0; j < 2; ++j) gl_lds16(bsrc[j] + k0, bdst[j]);
        __syncthreads();
        #pragma unroll
        for (int ks = 0; ks < 2; ++ks) {
            int cph = ((quad + 4 * ks) ^ xor7) << 3;
            s16x8 a[4], b[2];
            #pragma unroll
            for (int i = 0; i < 4; ++i)
                a[i] = *(const s16x8*)&sa[(wm * 64 + i * 16 + l16) * 64 + cph];
            #pragma unroll
            for (int j = 0; j < 2; ++j)
                b[j] = *(const s16x8*)&sb[(wn * 32 + j * 16 + l16) * 64 + cph];
            #pragma unroll
            for (int i = 0; i < 4; ++i)
                #pragma unroll
                for (int j = 0; j < 2; ++j)
                    acc[i][j] = __builtin_amdgcn_mfma_f32_16x16x32_bf16(a[i], b[j], acc[i][j], 0, 0, 0);
        }
        __syncthreads();
    }

    #pragma unroll
    for (int i = 0; i < 4; ++i) {
        #pragma unroll
        for (int r = 0; r < 4; ++r) {
            int row = wm * 64 + i * 16 + quad * 4 + r;
            if (m0 + row < cnt) {
                size_t base = (size_t)(off + m0 + row) * H + n0 + wn * 32;
                #pragma unroll
                for (int j = 0; j < 2; ++j)
                    y[base + j * 16 + l16] = f2bf(acc[i][j][r]);
            }
        }
    }
}

// ---------------- Combine: out[t] = w0*y[p0] + w1*y[p1] ----------------
__global__ __launch_bounds__(256) void combine_kernel(
    const unsigned short* __restrict__ y, const int* __restrict__ top_pos,
    const float* __restrict__ top_w, float* __restrict__ out)
{
    int t = blockIdx.x, tid = threadIdx.x;
    int p0 = top_pos[2*t], p1 = top_pos[2*t+1];
    float w0 = top_w[2*t], w1 = top_w[2*t+1];
    ushort4 a = ((const ushort4*)(y + (size_t)p0 * H))[tid];
    ushort4 b = ((const ushort4*)(y + (size_t)p1 * H))[tid];
    float4 o;
    o.x = w0 * bf2f(a.x) + w1 * bf2f(b.x);
    o.y = w0 * bf2f(a.y) + w1 * bf2f(b.y);
    o.z = w0 * bf2f(a.z) + w1 * bf2f(b.z);
    o.w = w0 * bf2f(a.w) + w1 * bf2f(b.w);
    ((float4*)(out + (size_t)t * H))[tid] = o;
}

extern "C" void kernel_launch(void* const* d_in, const int* in_sizes, int n_in,
                              void* d_out, int out_size, void* d_ws, size_t ws_size,
                              hipStream_t stream) {
    const float* x  = (const float*)d_in[0];
    const float* gw = (const float*)d_in[1];
    const float* w1 = (const float*)d_in[2];
    const float* w2 = (const float*)d_in[3];
    const float* w3 = (const float*)d_in[4];
    float* out    = (float*)d_out;              // T*H
    float* logits = out + (size_t)T * H;        // T*E

    // workspace layout
    int* counts   = (int*)d_ws;                 // [8]
    int* cursors  = counts + 8;                 // [8]
    int* offsets  = counts + 16;                // [9]
    int* top_id   = counts + 32;                // [2T]
    int* top_pos  = top_id + 2*T;               // [2T]
    float* top_w  = (float*)(top_pos + 2*T);    // [2T]
    unsigned short* xg  = (unsigned short*)(top_w + 2*T);          // [NSLOT+PAD][H]
    unsigned short* mid = xg  + (size_t)(NSLOT + SLOT_PAD) * H;    // [NSLOT+PAD][FF]
    unsigned short* y   = mid + (size_t)(NSLOT + SLOT_PAD) * FF;   // [NSLOT][H]
    unsigned short* w1b = y   + (size_t)NSLOT * H;                 // [E*FF*H]
    unsigned short* w3b = w1b + (size_t)E * FF * H;
    unsigned short* w2b = w3b + (size_t)E * FF * H;

    hipMemsetAsync(counts, 0, 16 * sizeof(int), stream);

    convert_kernel<<<dim3((E*FF*H)/(256*8), 3), 256, 0, stream>>>(w1, w3, w2, w1b, w3b, w2b);
    router_kernel<<<T, 256, 0, stream>>>(x, gw, logits, top_id, top_w, counts);
    scan_kernel<<<1, 64, 0, stream>>>(counts, offsets, cursors);
    assign_kernel<<<T, 256, 0, stream>>>(x, top_id, offsets, cursors, top_pos, xg);
    gemm1_kernel<<<dim3(FF / 64, 16, E), 256, 0, stream>>>(xg, w1b, w3b, offsets, mid);
    gemm2_kernel<<<dim3(H / 64, 16, E), 256, 0, stream>>>(mid, w2b, offsets, y);
    combine_kernel<<<T, 256, 0, stream>>>(y, top_pos, top_w, out);
}

// Round 4
// 422.895 us; speedup vs baseline: 1.0938x; 1.0081x over previous
//
#include <hip/hip_runtime.h>
#include <hip/hip_bf16.h>
#include <math.h>

#define H 1024
#define FF 2048
#define E 8
#define T 2048
#define NSLOT (2*T)
#define SLOT_PAD 128

// K1 block ranges
#define WCONV_BLKS 12288   // 3 tensors x 4096 blocks (256 thr x 16 elems)
#define XCONV_BLKS 512     // T*H/(256*16)
#define ROUTER_BLKS T
#define K1_BLKS (WCONV_BLKS + XCONV_BLKS + ROUTER_BLKS)

typedef __attribute__((ext_vector_type(8))) short s16x8;
typedef __attribute__((ext_vector_type(4))) float f32x4;
typedef __attribute__((ext_vector_type(4))) unsigned int u32x4;

static __device__ __forceinline__ unsigned short f2bf(float f) {
    union { float f; unsigned u; } v; v.f = f;
    unsigned r = v.u + 0x7fff + ((v.u >> 16) & 1);
    return (unsigned short)(r >> 16);
}
static __device__ __forceinline__ float bf2f(unsigned short s) {
    union { unsigned u; float f; } v; v.u = ((unsigned)s) << 16;
    return v.f;
}
static __device__ __forceinline__ unsigned pack2(float a, float b) {
    return (unsigned)f2bf(a) | ((unsigned)f2bf(b) << 16);
}

typedef __attribute__((address_space(3))) unsigned int lds_uint;
typedef const __attribute__((address_space(1))) unsigned int glob_uint;
static __device__ __forceinline__ void gl_lds16(const void* g, void* l) {
    __builtin_amdgcn_global_load_lds((glob_uint*)g, (lds_uint*)l, 16, 0, 0);
}

// inline exclusive prefix over counts -> off/cnt for expert e
static __device__ __forceinline__ void expert_range(const int* __restrict__ counts,
                                                    int e, int& off, int& cnt) {
    int acc = 0;
    #pragma unroll
    for (int i = 0; i < E; ++i) {
        int c = counts[i];
        if (i < e) acc += c;
        if (i == e) cnt = c;
    }
    off = acc;
}

// ---------------- K1: fused weight/x convert + router ----------------
__global__ __launch_bounds__(256) void prep_kernel(
    const float* __restrict__ x, const float* __restrict__ gw,
    const float* __restrict__ w1, const float* __restrict__ w3,
    const float* __restrict__ w2,
    unsigned short* __restrict__ w1b, unsigned short* __restrict__ w3b,
    unsigned short* __restrict__ w2b, unsigned short* __restrict__ xb,
    float* __restrict__ logits_out, int* __restrict__ top_id,
    float* __restrict__ top_w, int* __restrict__ counts)
{
    int b = blockIdx.x;
    int tid = threadIdx.x;
    if (b < WCONV_BLKS + XCONV_BLKS) {
        const float* s; unsigned short* d; size_t i;
        if (b < WCONV_BLKS) {
            int r = b >> 12;
            s = (r == 0) ? w1 : (r == 1) ? w3 : w2;
            d = (r == 0) ? w1b : (r == 1) ? w3b : w2b;
            i = ((size_t)(b & 4095) * 256 + tid) * 16;
        } else {
            s = x; d = xb;
            i = ((size_t)(b - WCONV_BLKS) * 256 + tid) * 16;
        }
        f32x4 a0 = __builtin_nontemporal_load((const f32x4*)(s + i));
        f32x4 a1 = __builtin_nontemporal_load((const f32x4*)(s + i + 4));
        f32x4 a2 = __builtin_nontemporal_load((const f32x4*)(s + i + 8));
        f32x4 a3 = __builtin_nontemporal_load((const f32x4*)(s + i + 12));
        u32x4 r0, r1;
        r0.x = pack2(a0.x, a0.y); r0.y = pack2(a0.z, a0.w);
        r0.z = pack2(a1.x, a1.y); r0.w = pack2(a1.z, a1.w);
        r1.x = pack2(a2.x, a2.y); r1.y = pack2(a2.z, a2.w);
        r1.z = pack2(a3.x, a3.y); r1.w = pack2(a3.z, a3.w);
        *(u32x4*)(d + i) = r0;
        *(u32x4*)(d + i + 8) = r1;
        return;
    }
    // ---- router ----
    int t = b - (WCONV_BLKS + XCONV_BLKS);
    int e = tid >> 5;
    int l32 = tid & 31;
    const float* xr = x + (size_t)t * H;
    const float* gr = gw + (size_t)e * H;
    float s = 0.f;
    for (int h = l32; h < H; h += 32) s += xr[h] * gr[h];
    for (int off = 16; off; off >>= 1) s += __shfl_down(s, off, 32);
    __shared__ float lg[E];
    if (l32 == 0) lg[e] = s;
    __syncthreads();
    if (tid < E) logits_out[(size_t)t * E + tid] = lg[tid];
    if (tid == 0) {
        int i1 = 0; float b1 = lg[0];
        for (int i = 1; i < E; ++i) if (lg[i] > b1) { b1 = lg[i]; i1 = i; }
        int i2 = -1; float b2 = -INFINITY;
        for (int i = 0; i < E; ++i) if (i != i1 && lg[i] > b2) { b2 = lg[i]; i2 = i; }
        float p2 = expf(b2 - b1);
        float inv = 1.f / (1.f + p2);
        top_id[2*t]   = i1;  top_id[2*t+1] = i2;
        top_w[2*t]    = inv; top_w[2*t+1]  = p2 * inv;
        atomicAdd(&counts[i1], 1);
        atomicAdd(&counts[i2], 1);
    }
}

// ---------------- K2: slot assignment (scan inlined) ----------------
__global__ __launch_bounds__(256) void assign_kernel(
    const int* __restrict__ top_id, const int* __restrict__ counts,
    int* __restrict__ cursors, int* __restrict__ top_pos,
    int* __restrict__ slot_token)
{
    int t = blockIdx.x * 256 + threadIdx.x;
    if (t >= T) return;
    int offs[E];
    {
        int acc = 0;
        #pragma unroll
        for (int i = 0; i < E; ++i) { offs[i] = acc; acc += counts[i]; }
    }
    #pragma unroll
    for (int k = 0; k < 2; ++k) {
        int e = top_id[2*t + k];
        int p = offs[e] + atomicAdd(&cursors[e], 1);
        top_pos[2*t + k] = p;
        slot_token[p] = t;
    }
}

// ---------------- K3: GEMM1 mid = silu(X@w1^T)*(X@w3^T), indirect A staging ----------------
__global__ __launch_bounds__(256) void gemm1_kernel(
    const unsigned short* __restrict__ xb, const int* __restrict__ slot_token,
    const unsigned short* __restrict__ w1b, const unsigned short* __restrict__ w3b,
    const int* __restrict__ counts, unsigned short* __restrict__ mid)
{
    int e = blockIdx.z;
    int off, cnt;
    expert_range(counts, e, off, cnt);
    int m0 = blockIdx.y * 128;
    if (m0 >= cnt) return;
    int f0 = blockIdx.x * 64;

    __shared__ __align__(16) unsigned short sx[128 * 64];
    __shared__ __align__(16) unsigned short s1[64 * 64];
    __shared__ __align__(16) unsigned short s3[64 * 64];

    int tid = threadIdx.x;
    int wv = tid >> 6, ln = tid & 63;
    int quad = ln >> 4, l16 = ln & 15;
    int wm = wv & 1, wn = wv >> 1;
    int xor7 = l16 & 7;

    const unsigned short* xsrc[4]; unsigned short* xdst[4];
    #pragma unroll
    for (int j = 0; j < 4; ++j) {
        int row = wv * 32 + j * 8 + (ln >> 3);
        int slot = off + m0 + row;
        if (m0 + row >= cnt) slot = off;          // clamp to a valid slot
        int tok = slot_token[slot];
        int cl = (ln & 7) ^ (row & 7);
        xsrc[j] = xb + (size_t)tok * H + cl * 8;
        xdst[j] = &sx[(wv * 32 + j * 8) * 64];
    }
    const unsigned short *w1s[2], *w3s[2]; unsigned short *d1[2], *d3[2];
    #pragma unroll
    for (int j = 0; j < 2; ++j) {
        int row = wv * 16 + j * 8 + (ln >> 3);
        int cl = (ln & 7) ^ (row & 7);
        w1s[j] = w1b + ((size_t)e * FF + f0 + row) * H + cl * 8;
        w3s[j] = w3b + ((size_t)e * FF + f0 + row) * H + cl * 8;
        d1[j] = &s1[(wv * 16 + j * 8) * 64];
        d3[j] = &s3[(wv * 16 + j * 8) * 64];
    }

    f32x4 acc1[4][2], acc3[4][2];
    #pragma unroll
    for (int i = 0; i < 4; ++i)
        #pragma unroll
        for (int j = 0; j < 2; ++j) {
            acc1[i][j] = (f32x4){0.f, 0.f, 0.f, 0.f};
            acc3[i][j] = (f32x4){0.f, 0.f, 0.f, 0.f};
        }

    for (int k0 = 0; k0 < H; k0 += 64) {
        #pragma unroll
        for (int j = 0; j < 4; ++j) gl_lds16(xsrc[j] + k0, xdst[j]);
        #pragma unroll
        for (int j = 0; j < 2; ++j) { gl_lds16(w1s[j] + k0, d1[j]); gl_lds16(w3s[j] + k0, d3[j]); }
        __syncthreads();
        #pragma unroll
        for (int ks = 0; ks < 2; ++ks) {
            int cph = ((quad + 4 * ks) ^ xor7) << 3;
            s16x8 a[4], b1v[2], b3v[2];
            #pragma unroll
            for (int i = 0; i < 4; ++i)
                a[i] = *(const s16x8*)&sx[(wm * 64 + i * 16 + l16) * 64 + cph];
            #pragma unroll
            for (int j = 0; j < 2; ++j) {
                b1v[j] = *(const s16x8*)&s1[(wn * 32 + j * 16 + l16) * 64 + cph];
                b3v[j] = *(const s16x8*)&s3[(wn * 32 + j * 16 + l16) * 64 + cph];
            }
            #pragma unroll
            for (int i = 0; i < 4; ++i)
                #pragma unroll
                for (int j = 0; j < 2; ++j) {
                    acc1[i][j] = __builtin_amdgcn_mfma_f32_16x16x32_bf16(a[i], b1v[j], acc1[i][j], 0, 0, 0);
                    acc3[i][j] = __builtin_amdgcn_mfma_f32_16x16x32_bf16(a[i], b3v[j], acc3[i][j], 0, 0, 0);
                }
        }
        __syncthreads();
    }

    #pragma unroll
    for (int i = 0; i < 4; ++i) {
        #pragma unroll
        for (int r = 0; r < 4; ++r) {
            int row = wm * 64 + i * 16 + quad * 4 + r;
            if (m0 + row < cnt) {
                size_t base = (size_t)(off + m0 + row) * FF + f0 + wn * 32;
                #pragma unroll
                for (int j = 0; j < 2; ++j) {
                    float h = acc1[i][j][r];
                    float g = acc3[i][j][r];
                    float v = h / (1.f + __expf(-h)) * g;
                    mid[base + j * 16 + l16] = f2bf(v);
                }
            }
        }
    }
}

// ---------------- K4: GEMM2 y[slot] = mid[slot] @ w2^T ----------------
__global__ __launch_bounds__(256) void gemm2_kernel(
    const unsigned short* __restrict__ mid, const unsigned short* __restrict__ w2b,
    const int* __restrict__ counts, unsigned short* __restrict__ y)
{
    int e = blockIdx.z;
    int off, cnt;
    expert_range(counts, e, off, cnt);
    int m0 = blockIdx.y * 128;
    if (m0 >= cnt) return;
    int n0 = blockIdx.x * 64;

    __shared__ __align__(16) unsigned short sa[128 * 64];
    __shared__ __align__(16) unsigned short sb[64 * 64];

    int tid = threadIdx.x;
    int wv = tid >> 6, ln = tid & 63;
    int quad = ln >> 4, l16 = ln & 15;
    int wm = wv & 1, wn = wv >> 1;
    int xor7 = l16 & 7;

    const unsigned short* asrc[4]; unsigned short* adst[4];
    #pragma unroll
    for (int j = 0; j < 4; ++j) {
        int row = wv * 32 + j * 8 + (ln >> 3);
        int cl = (ln & 7) ^ (row & 7);
        asrc[j] = mid + (size_t)(off + m0 + row) * FF + cl * 8;
        adst[j] = &sa[(wv * 32 + j * 8) * 64];
    }
    const unsigned short* bsrc[2]; unsigned short* bdst[2];
    #pragma unroll
    for (int j = 0; j < 2; ++j) {
        int row = wv * 16 + j * 8 + (ln >> 3);
        int cl = (ln & 7) ^ (row & 7);
        bsrc[j] = w2b + ((size_t)e * H + n0 + row) * FF + cl * 8;
        bdst[j] = &sb[(wv * 16 + j * 8) * 64];
    }

    f32x4 acc[4][2];
    #pragma unroll
    for (int i = 0; i < 4; ++i)
        #pragma unroll
        for (int j = 0; j < 2; ++j) acc[i][j] = (f32x4){0.f, 0.f, 0.f, 0.f};

    for (int k0 = 0; k0 < FF; k0 += 64) {
        #pragma unroll
        for (int j = 0; j < 4; ++j) gl_lds16(asrc[j] + k0, adst[j]);
        #pragma unroll
        for (int j = 0; j < 2; ++j) gl_lds16(bsrc[j] + k0, bdst[j]);
        __syncthreads();
        #pragma unroll
        for (int ks = 0; ks < 2; ++ks) {
            int cph = ((quad + 4 * ks) ^ xor7) << 3;
            s16x8 a[4], b[2];
            #pragma unroll
            for (int i = 0; i < 4; ++i)
                a[i] = *(const s16x8*)&sa[(wm * 64 + i * 16 + l16) * 64 + cph];
            #pragma unroll
            for (int j = 0; j < 2; ++j)
                b[j] = *(const s16x8*)&sb[(wn * 32 + j * 16 + l16) * 64 + cph];
            #pragma unroll
            for (int i = 0; i < 4; ++i)
                #pragma unroll
                for (int j = 0; j < 2; ++j)
                    acc[i][j] = __builtin_amdgcn_mfma_f32_16x16x32_bf16(a[i], b[j], acc[i][j], 0, 0, 0);
        }
        __syncthreads();
    }

    #pragma unroll
    for (int i = 0; i < 4; ++i) {
        #pragma unroll
        for (int r = 0; r < 4; ++r) {
            int row = wm * 64 + i * 16 + quad * 4 + r;
            if (m0 + row < cnt) {
                size_t base = (size_t)(off + m0 + row) * H + n0 + wn * 32;
                #pragma unroll
                for (int j = 0; j < 2; ++j)
                    y[base + j * 16 + l16] = f2bf(acc[i][j][r]);
            }
        }
    }
}

// ---------------- K5: combine out[t] = w0*y[p0] + w1*y[p1] ----------------
__global__ __launch_bounds__(256) void combine_kernel(
    const unsigned short* __restrict__ y, const int* __restrict__ top_pos,
    const float* __restrict__ top_w, float* __restrict__ out)
{
    int t = blockIdx.x, tid = threadIdx.x;
    int p0 = top_pos[2*t], p1 = top_pos[2*t+1];
    float w0 = top_w[2*t], w1 = top_w[2*t+1];
    ushort4 a = ((const ushort4*)(y + (size_t)p0 * H))[tid];
    ushort4 b = ((const ushort4*)(y + (size_t)p1 * H))[tid];
    float4 o;
    o.x = w0 * bf2f(a.x) + w1 * bf2f(b.x);
    o.y = w0 * bf2f(a.y) + w1 * bf2f(b.y);
    o.z = w0 * bf2f(a.z) + w1 * bf2f(b.z);
    o.w = w0 * bf2f(a.w) + w1 * bf2f(b.w);
    ((float4*)(out + (size_t)t * H))[tid] = o;
}

extern "C" void kernel_launch(void* const* d_in, const int* in_sizes, int n_in,
                              void* d_out, int out_size, void* d_ws, size_t ws_size,
                              hipStream_t stream) {
    const float* x  = (const float*)d_in[0];
    const float* gw = (const float*)d_in[1];
    const float* w1 = (const float*)d_in[2];
    const float* w2 = (const float*)d_in[3];
    const float* w3 = (const float*)d_in[4];
    float* out    = (float*)d_out;              // T*H
    float* logits = out + (size_t)T * H;        // T*E

    // workspace layout
    int* counts      = (int*)d_ws;              // [8]
    int* cursors     = counts + 8;              // [8]
    int* top_id      = counts + 16;             // [2T]
    int* top_pos     = top_id + 2*T;            // [2T]
    int* slot_token  = top_pos + 2*T;           // [NSLOT]
    float* top_w     = (float*)(slot_token + NSLOT);               // [2T]
    unsigned short* xb  = (unsigned short*)(top_w + 2*T);          // [T][H]
    unsigned short* mid = xb  + (size_t)T * H;                     // [NSLOT+PAD][FF]
    unsigned short* y   = mid + (size_t)(NSLOT + SLOT_PAD) * FF;   // [NSLOT][H]
    unsigned short* w1b = y   + (size_t)NSLOT * H;                 // [E*FF*H]
    unsigned short* w3b = w1b + (size_t)E * FF * H;
    unsigned short* w2b = w3b + (size_t)E * FF * H;

    (void)hipMemsetAsync(counts, 0, 16 * sizeof(int), stream);

    prep_kernel<<<K1_BLKS, 256, 0, stream>>>(x, gw, w1, w3, w2,
                                             w1b, w3b, w2b, xb,
                                             logits, top_id, top_w, counts);
    assign_kernel<<<(T + 255) / 256, 256, 0, stream>>>(top_id, counts, cursors,
                                                       top_pos, slot_token);
    gemm1_kernel<<<dim3(FF / 64, 16, E), 256, 0, stream>>>(xb, slot_token,
                                                           w1b, w3b, counts, mid);
    gemm2_kernel<<<dim3(H / 64, 16, E), 256, 0, stream>>>(mid, w2b, counts, y);
    combine_kernel<<<T, 256, 0, stream>>>(y, top_pos, top_w, out);
}